// Round 13
// baseline (766.984 us; speedup 1.0000x reference)
//
#include <hip/hip_runtime.h>
#include <hip/hip_bf16.h>

#define B_   1024
#define L_   200
#define H_   128
#define BL_  204800   // B_*L_
#define G3_  384

typedef __bf16 bf16x8 __attribute__((ext_vector_type(8)));
typedef __bf16 bf16x4 __attribute__((ext_vector_type(4)));
typedef float  f32x4  __attribute__((ext_vector_type(4)));

__device__ __forceinline__ float sigf(float x) {
    return __builtin_amdgcn_rcpf(1.f + __expf(-x));
}
__device__ __forceinline__ float tanh_fast(float x) {
    float e = __expf(-2.f * x);
    return (1.f - e) * __builtin_amdgcn_rcpf(1.f + e);
}
__device__ __forceinline__ bf16x8 cvt8(float4 a, float4 b) {
    bf16x8 v;
    v[0] = (__bf16)a.x; v[1] = (__bf16)a.y; v[2] = (__bf16)a.z; v[3] = (__bf16)a.w;
    v[4] = (__bf16)b.x; v[5] = (__bf16)b.y; v[6] = (__bf16)b.z; v[7] = (__bf16)b.w;
    return v;
}

// ---------------- K0: sentinel (workspace too small -> distinguishable absmax)
__global__ __launch_bounds__(256) void k_sentinel(float* __restrict__ out, int n) {
    const int i = blockIdx.x * 256 + threadIdx.x;
    if (i < n) out[i] = -5.0f;
}

// ---------------- K1: dec_linear
__global__ __launch_bounds__(256) void k_declin(
    const float* __restrict__ rcv, const float* __restrict__ Wl,
    const float* __restrict__ bl, float* __restrict__ code) {
    __shared__ float rs[4][400];
    const int tid = threadIdx.x;
    const int b0 = blockIdx.x * 4;
    for (int i = tid; i < 1600; i += 256) ((float*)rs)[i] = rcv[(size_t)b0 * 400 + i];
    __syncthreads();
    #pragma unroll
    for (int rep = 0; rep < 2; ++rep) {
        const int j = tid + rep * 256;
        if (j < 400) {
            float a0 = 0.f, a1 = 0.f, a2 = 0.f, a3 = 0.f;
            const float4* wp = (const float4*)(Wl + (size_t)j * 400);
            for (int k = 0; k < 100; ++k) {
                float4 w4 = wp[k];
                const int kk = k * 4;
                a0 += w4.x*rs[0][kk] + w4.y*rs[0][kk+1] + w4.z*rs[0][kk+2] + w4.w*rs[0][kk+3];
                a1 += w4.x*rs[1][kk] + w4.y*rs[1][kk+1] + w4.z*rs[1][kk+2] + w4.w*rs[1][kk+3];
                a2 += w4.x*rs[2][kk] + w4.y*rs[2][kk+1] + w4.z*rs[2][kk+2] + w4.w*rs[2][kk+3];
                a3 += w4.x*rs[3][kk] + w4.y*rs[3][kk+1] + w4.z*rs[3][kk+2] + w4.w*rs[3][kk+3];
            }
            const float bb = bl[j];
            code[(size_t)(b0+0)*400 + j] = a0 + bb;
            code[(size_t)(b0+1)*400 + j] = a1 + bb;
            code[(size_t)(b0+2)*400 + j] = a2 + bb;
            code[(size_t)(b0+3)*400 + j] = a3 + bb;
        }
    }
}

// ---------------- K2: layer0 GRU — BOTH DIRECTIONS FUSED per block: tile=4,
// 256 blocks x 512 threads; waves 0..3 = forward chain, waves 4..7 = backward
// chain (each wave 2 col-groups of its dir). Two independent dependency chains
// share each barrier: when one chain's latency stalls, the other's instructions
// issue. One barrier/step, h double-buffered per dir, h0 stores batched via
// per-dir LDS stage (flush every 8 steps).
__global__ __launch_bounds__(512, 2) void k_gru0(
    const float* __restrict__ code,
    const float* __restrict__ Wih_f, const float* __restrict__ Whh_f,
    const float* __restrict__ bih_f, const float* __restrict__ bhh_f,
    const float* __restrict__ Wih_b, const float* __restrict__ Whh_b,
    const float* __restrict__ bih_b, const float* __restrict__ bhh_b,
    __bf16* __restrict__ h0) {
    const int b0 = blockIdx.x * 4;
    const int tid = threadIdx.x;
    const int d  = tid >> 8;           // direction (waves 0-3 fwd, 4-7 bwd)
    const int ltid = tid & 255;
    const int w  = (tid >> 6) & 3;     // wave within dir group
    const int ln = tid & 63, q = ln >> 4, r16 = ln & 15;

    const float* Wih = d ? Wih_b : Wih_f;
    const float* Whh = d ? Whh_b : Whh_f;
    const float* bih = d ? bih_b : bih_f;
    const float* bhh = d ? bhh_b : bhh_f;

    __shared__ __bf16 h_bf[2][2][16][136];   // [dir][buf][row][col] 17,408 B
    __shared__ float  code_s[4][400];        //  6,400 B (shared by both dirs)
    __shared__ __bf16 h_st[2][2][8][4][128]; // [dir][grp-par][s][row][col] 32,768 B
                                             // total 56,576 B

    for (int i = tid; i < 4 * 400; i += 512) ((float*)code_s)[i] = code[(size_t)b0 * 400 + i];
    for (int i = tid; i < 2 * 2 * 16 * 136; i += 512) ((__bf16*)h_bf)[i] = (__bf16)0.f;

    bf16x8 wfr[2][3][4];
    float wr0[2], wr1[2], wz0[2], wz1[2], wn0[2], wn1[2];
    float xbr[2], xbz[2], xbn[2], bnv[2];
    float hreg[2][4];
    #pragma unroll
    for (int ci = 0; ci < 2; ++ci) {
        const int jj = (2 * w + ci) * 16 + r16;
        wr0[ci] = Wih[jj * 2];           wr1[ci] = Wih[jj * 2 + 1];
        wz0[ci] = Wih[(jj + 128) * 2];   wz1[ci] = Wih[(jj + 128) * 2 + 1];
        wn0[ci] = Wih[(jj + 256) * 2];   wn1[ci] = Wih[(jj + 256) * 2 + 1];
        xbr[ci] = bih[jj] + bhh[jj];
        xbz[ci] = bih[jj + 128] + bhh[jj + 128];
        xbn[ci] = bih[jj + 256];
        bnv[ci] = bhh[jj + 256];
        #pragma unroll
        for (int reg = 0; reg < 4; ++reg) hreg[ci][reg] = 0.f;
        #pragma unroll
        for (int g = 0; g < 3; ++g) {
            const int j = ((2 * w + ci) + g * 8) * 16 + r16;
            const float* p = Whh + (size_t)j * H_;
            #pragma unroll
            for (int kt = 0; kt < 4; ++kt) {
                float4 x0 = *(const float4*)(p + kt * 32 + q * 8);
                float4 x1 = *(const float4*)(p + kt * 32 + q * 8 + 4);
                wfr[ci][g][kt] = cvt8(x0, x1);
            }
        }
    }
    __syncthreads();

    for (int t = 0; t < L_; ++t) {
        const int cur = t & 1, nxt = cur ^ 1;
        // flush previous 8-step group for this dir (retires during this step)
        if ((t & 7) == 0 && t > 0) {
            const int g8 = (t >> 3) - 1;
            const int buf = g8 & 1;
            const int pr = ltid >> 3, inner = ltid & 7;   // 32 pairs x 8 threads
            const int s = pr >> 2, row = pr & 3;
            const int tb = g8 * 8 + s;
            const int l = d ? (L_ - 1 - tb) : tb;
            const __bf16* src = &h_st[d][buf][s][row][inner * 16];
            __bf16* dst = &h0[((size_t)(b0 + row) * L_ + l) * 256 + d * 128 + inner * 16];
            *(bf16x8*)(dst)     = *(const bf16x8*)(src);
            *(bf16x8*)(dst + 8) = *(const bf16x8*)(src + 8);
        }
        const int l = d ? (L_ - 1 - t) : t;
        bf16x8 af[4];
        #pragma unroll
        for (int kt = 0; kt < 4; ++kt)
            af[kt] = *(const bf16x8*)&h_bf[d][cur][r16][kt * 32 + q * 8];

        #pragma unroll
        for (int ci = 0; ci < 2; ++ci) {
            const int jj = (2 * w + ci) * 16 + r16;
            f32x4 ar = {0.f,0.f,0.f,0.f}, az = {0.f,0.f,0.f,0.f}, an = {0.f,0.f,0.f,0.f};
            #pragma unroll
            for (int kt = 0; kt < 4; ++kt) {
                ar = __builtin_amdgcn_mfma_f32_16x16x32_bf16(af[kt], wfr[ci][0][kt], ar, 0, 0, 0);
                az = __builtin_amdgcn_mfma_f32_16x16x32_bf16(af[kt], wfr[ci][1][kt], az, 0, 0, 0);
                an = __builtin_amdgcn_mfma_f32_16x16x32_bf16(af[kt], wfr[ci][2][kt], an, 0, 0, 0);
            }
            if (q == 0) {   // real rows 0..3 (MFMA C-layout ties m to q*4+reg)
                #pragma unroll
                for (int reg = 0; reg < 4; ++reg) {
                    const float c0 = code_s[reg][l * 2], c1 = code_s[reg][l * 2 + 1];
                    const float r = sigf(c0 * wr0[ci] + c1 * wr1[ci] + xbr[ci] + ar[reg]);
                    const float z = sigf(c0 * wz0[ci] + c1 * wz1[ci] + xbz[ci] + az[reg]);
                    const float n = tanh_fast(c0 * wn0[ci] + c1 * wn1[ci] + xbn[ci] + r * (an[reg] + bnv[ci]));
                    const float hv = n + z * (hreg[ci][reg] - n);
                    hreg[ci][reg] = hv;
                    h_bf[d][nxt][reg][jj] = (__bf16)hv;
                    h_st[d][(t >> 3) & 1][t & 7][reg][jj] = (__bf16)hv;
                }
            }
        }
        __syncthreads();   // single barrier: both dirs' h[nxt] + stages visible
    }
    {   // final flush: group 24 (t=192..199), buf = 24&1 = 0
        const int pr = ltid >> 3, inner = ltid & 7;
        const int s = pr >> 2, row = pr & 3;
        const int tb = 192 + s;
        const int l = d ? (L_ - 1 - tb) : tb;
        const __bf16* src = &h_st[d][0][s][row][inner * 16];
        __bf16* dst = &h0[((size_t)(b0 + row) * L_ + l) * 256 + d * 128 + inner * 16];
        *(bf16x8*)(dst)     = *(const bf16x8*)(src);
        *(bf16x8*)(dst + 8) = *(const bf16x8*)(src + 8);
    }
}

// ---------------- K3: convert Wih1 (both dirs) fp32 -> bf16  [2][384][256]
__global__ __launch_bounds__(256) void k_cvtW(
    const float* __restrict__ Wfp, const float* __restrict__ Wbp,
    __bf16* __restrict__ out) {
    const int j = blockIdx.x * 256 + threadIdx.x;
    const int base = j * 4;
    const int dir = base >= 98304;
    const int idx = dir ? base - 98304 : base;
    float4 v = *(const float4*)((dir ? Wbp : Wfp) + idx);
    bf16x4 o;
    o[0] = (__bf16)v.x; o[1] = (__bf16)v.y; o[2] = (__bf16)v.z; o[3] = (__bf16)v.w;
    *(bf16x4*)&out[base] = o;
}

// ---------------- K4: layer1 GRU (r12 version, unchanged): tile=8, 8 waves,
// Wih1 B-frags register-resident, k8-outer GEMM, A-chunk double-buffered with
// register prefetch parked at s==2, chunk = 4 steps, one barrier per step.
__global__ __launch_bounds__(512, 2) void k_gru1f(
    const __bf16* __restrict__ h0,       // [B][L][256]
    const __bf16* __restrict__ Wihbf,    // [2][384][256] bf16
    const float* __restrict__ bih_f, const float* __restrict__ bhh_f,
    const float* __restrict__ bih_b, const float* __restrict__ bhh_b,
    const float* __restrict__ Whh_f, const float* __restrict__ Whh_b,
    const float* __restrict__ Wfin,
    float* __restrict__ partial) {
    const int dir = blockIdx.y;
    const int b0 = blockIdx.x * 8;
    const float* Whh = dir ? Whh_b : Whh_f;
    const float* bih = dir ? bih_b : bih_f;
    const float* bhh = dir ? bhh_b : bhh_f;
    const __bf16* Wb = Wihbf + (size_t)dir * 384 * 256;

    const int tid = threadIdx.x;
    const int w = tid >> 6, ln = tid & 63, q = ln >> 4, r16 = ln & 15;
    const int jj = w * 16 + r16;   // this wave's 16 recurrence columns

    __shared__ __bf16 xa[2][32][264];    // 33,792 B  A-chunk dbuf (rows = s*8+bt)
    __shared__ __bf16 xgT[384][36];      // 27,648 B  [col][chunk row (32) + pad]
    __shared__ __bf16 h_bf[2][16][136];  //  8,704 B  (rows 8..15 zero pad)
    __shared__ float  wacc[2][8][8];     //    512 B  -> total 70,656 B

    for (int i = tid; i < 2 * 16 * 136; i += 512) ((__bf16*)h_bf)[i] = (__bf16)0.f;

    bf16x8 wfr[3][4];
    bf16x8 wB[3][8];                      // register-resident Wih1 B-frags
    const float xbr = bih[jj] + bhh[jj];
    const float xbz = bih[jj + 128] + bhh[jj + 128];
    const float xbn = bih[jj + 256];
    const float bnv = bhh[jj + 256];
    const float wfv = Wfin[dir * 128 + jj];
    float hreg[4] = {0.f, 0.f, 0.f, 0.f};
    #pragma unroll
    for (int g = 0; g < 3; ++g) {
        const int j = (w + g * 8) * 16 + r16;
        const float* p = Whh + (size_t)j * H_;
        #pragma unroll
        for (int kt = 0; kt < 4; ++kt) {
            float4 x0 = *(const float4*)(p + kt * 32 + q * 8);
            float4 x1 = *(const float4*)(p + kt * 32 + q * 8 + 4);
            wfr[g][kt] = cvt8(x0, x1);
        }
    }
    #pragma unroll
    for (int n = 0; n < 3; ++n) {
        const int ct = w * 3 + n;
        const __bf16* wp = Wb + (size_t)(ct * 16 + r16) * 256 + q * 8;
        #pragma unroll
        for (int k8 = 0; k8 < 8; ++k8)
            wB[n][k8] = *(const bf16x8*)(wp + k8 * 32);
    }
    // prologue: stage chunk 0 into xa[0]
    {
        const int r = tid >> 4, seg = tid & 15;       // 32 rows x 16 threads
        const int s = r >> 3, bt = r & 7;
        const int l = dir ? (L_ - 1 - s) : s;         // t = s
        const __bf16* src = h0 + ((size_t)(b0 + bt) * L_ + l) * 256 + seg * 16;
        *(bf16x8*)&xa[0][r][seg * 16]     = *(const bf16x8*)(src);
        *(bf16x8*)&xa[0][r][seg * 16 + 8] = *(const bf16x8*)(src + 8);
    }
    __syncthreads();

    int gstep = 0;
    for (int c = 0; c < 50; ++c) {
        const int cb = c & 1, nb = cb ^ 1;
        // ---- issue prefetch loads for chunk c+1 (hidden under GEMM + 3 steps)
        bf16x8 pf0, pf1;
        const bool pv = (c + 1 < 50);
        const int prr = tid >> 4, prs = tid & 15;
        if (pv) {
            const int s = prr >> 3, bt = prr & 7;
            const int t = (c + 1) * 4 + s;
            const int l = dir ? (L_ - 1 - t) : t;
            const __bf16* src = h0 + ((size_t)(b0 + bt) * L_ + l) * 256 + prs * 16;
            pf0 = *(const bf16x8*)(src);
            pf1 = *(const bf16x8*)(src + 8);
        }

        // ---- chunk GEMM: xg[32 x 384] = xa[cb] @ Wih1^T; A read once per k8,
        // reused across the wave's 3 register-resident col-tiles.
        {
            f32x4 acc[3][2];
            #pragma unroll
            for (int n = 0; n < 3; ++n)
                #pragma unroll
                for (int mt = 0; mt < 2; ++mt) {
                    acc[n][mt][0]=0.f; acc[n][mt][1]=0.f;
                    acc[n][mt][2]=0.f; acc[n][mt][3]=0.f;
                }
            #pragma unroll
            for (int k8 = 0; k8 < 8; ++k8) {
                const bf16x8 a0 = *(const bf16x8*)&xa[cb][r16][k8 * 32 + q * 8];
                const bf16x8 a1 = *(const bf16x8*)&xa[cb][16 + r16][k8 * 32 + q * 8];
                #pragma unroll
                for (int n = 0; n < 3; ++n) {
                    acc[n][0] = __builtin_amdgcn_mfma_f32_16x16x32_bf16(a0, wB[n][k8], acc[n][0], 0, 0, 0);
                    acc[n][1] = __builtin_amdgcn_mfma_f32_16x16x32_bf16(a1, wB[n][k8], acc[n][1], 0, 0, 0);
                }
            }
            #pragma unroll
            for (int n = 0; n < 3; ++n) {
                const int ct = w * 3 + n;
                #pragma unroll
                for (int mt = 0; mt < 2; ++mt) {
                    bf16x4 o;
                    o[0] = (__bf16)acc[n][mt][0]; o[1] = (__bf16)acc[n][mt][1];
                    o[2] = (__bf16)acc[n][mt][2]; o[3] = (__bf16)acc[n][mt][3];
                    *(bf16x4*)&xgT[ct * 16 + r16][mt * 16 + q * 4] = o;
                }
            }
        }
        __syncthreads();   // xgT ready

        // ---- 4 recurrent steps, one barrier each
        for (int s = 0; s < 4; ++s, ++gstep) {
            const int cur = gstep & 1, nxt = cur ^ 1;
            const int par = s & 1;
            const int t = c * 4 + s;
            const int l = dir ? (L_ - 1 - t) : t;

            bf16x8 af[4];
            #pragma unroll
            for (int kt = 0; kt < 4; ++kt)
                af[kt] = *(const bf16x8*)&h_bf[cur][r16][kt * 32 + q * 8];

            f32x4 ar = {0.f,0.f,0.f,0.f}, az = {0.f,0.f,0.f,0.f}, an = {0.f,0.f,0.f,0.f};
            #pragma unroll
            for (int kt = 0; kt < 4; ++kt) {
                ar = __builtin_amdgcn_mfma_f32_16x16x32_bf16(af[kt], wfr[0][kt], ar, 0, 0, 0);
                az = __builtin_amdgcn_mfma_f32_16x16x32_bf16(af[kt], wfr[1][kt], az, 0, 0, 0);
                an = __builtin_amdgcn_mfma_f32_16x16x32_bf16(af[kt], wfr[2][kt], an, 0, 0, 0);
            }
            if (q < 2) {   // real rows 0..7
                bf16x4 xr4 = *(const bf16x4*)&xgT[jj      ][s * 8 + q * 4];
                bf16x4 xz4 = *(const bf16x4*)&xgT[jj + 128][s * 8 + q * 4];
                bf16x4 xn4 = *(const bf16x4*)&xgT[jj + 256][s * 8 + q * 4];
                #pragma unroll
                for (int reg = 0; reg < 4; ++reg) {
                    const int m = q * 4 + reg;
                    const float r = sigf((float)xr4[reg] + xbr + ar[reg]);
                    const float z = sigf((float)xz4[reg] + xbz + az[reg]);
                    const float n = tanh_fast((float)xn4[reg] + xbn + r * (an[reg] + bnv));
                    const float hv = n + z * (hreg[reg] - n);
                    hreg[reg] = hv;
                    h_bf[nxt][m][jj] = (__bf16)hv;
                }
                // fused final-linear partial dot (this wave's 16-col slice)
                #pragma unroll
                for (int reg = 0; reg < 4; ++reg) {
                    float v = hreg[reg] * wfv;
                    v += __shfl_xor(v, 1); v += __shfl_xor(v, 2);
                    v += __shfl_xor(v, 4); v += __shfl_xor(v, 8);
                    if (r16 == 0) wacc[par][w][q * 4 + reg] = v;
                }
            }
            // park prefetched chunk c+1 into xa[nb]; published by this barrier
            if (pv && s == 2) {
                *(bf16x8*)&xa[nb][prr][prs * 16]     = pf0;
                *(bf16x8*)&xa[nb][prr][prs * 16 + 8] = pf1;
            }
            __syncthreads();   // single barrier: h[nxt] + wacc[par] (+ xa park) visible
            if (tid < 8) {     // tiny store, drains during next interval
                float v = 0.f;
                #pragma unroll
                for (int ww = 0; ww < 8; ++ww) v += wacc[par][ww][tid];
                partial[(size_t)dir * BL_ + (size_t)(b0 + tid) * L_ + l] = v;
            }
        }
    }
}

// ---------------- K5: out = sigmoid(pf + pb + bf)
__global__ __launch_bounds__(256) void k_final(
    const float* __restrict__ partial, const float* __restrict__ bfp,
    float* __restrict__ out) {
    const int i = blockIdx.x * 256 + threadIdx.x;
    if (i < BL_) out[i] = sigf(partial[i] + partial[BL_ + i] + bfp[0]);
}

extern "C" void kernel_launch(void* const* d_in, const int* in_sizes, int n_in,
                              void* d_out, int out_size, void* d_ws, size_t ws_size,
                              hipStream_t stream) {
    const float* rcv   = (const float*)d_in[0];
    const float* Wl    = (const float*)d_in[1];
    const float* bl    = (const float*)d_in[2];
    const float* Wih0f = (const float*)d_in[3];
    const float* Whh0f = (const float*)d_in[4];
    const float* bih0f = (const float*)d_in[5];
    const float* bhh0f = (const float*)d_in[6];
    const float* Wih0b = (const float*)d_in[7];
    const float* Whh0b = (const float*)d_in[8];
    const float* bih0b = (const float*)d_in[9];
    const float* bhh0b = (const float*)d_in[10];
    const float* Wih1f = (const float*)d_in[11];
    const float* Whh1f = (const float*)d_in[12];
    const float* bih1f = (const float*)d_in[13];
    const float* bhh1f = (const float*)d_in[14];
    const float* Wih1b = (const float*)d_in[15];
    const float* Whh1b = (const float*)d_in[16];
    const float* bih1b = (const float*)d_in[17];
    const float* bhh1b = (const float*)d_in[18];
    const float* Wfin  = (const float*)d_in[19];
    const float* bfin  = (const float*)d_in[20];

    const size_t OFF_CODE = 0;                     // 1,638,400 B
    const size_t OFF_PART = 1638400;               // 1,638,400 B
    const size_t OFF_H0   = 3276800;               // 104,857,600 B
    const size_t OFF_WBF  = 108134400;             //     393,216 B
    const size_t WS_NEEDED = 108527616;            // ~103.5 MB total

    if (ws_size < WS_NEEDED) {
        k_sentinel<<<(out_size + 255) / 256, 256, 0, stream>>>((float*)d_out, out_size);
        return;
    }

    char* ws = (char*)d_ws;
    float*  code    = (float*)(ws + OFF_CODE);
    float*  partial = (float*)(ws + OFF_PART);
    __bf16* h0      = (__bf16*)(ws + OFF_H0);
    __bf16* Wihbf   = (__bf16*)(ws + OFF_WBF);

    k_declin<<<256, 256, 0, stream>>>(rcv, Wl, bl, code);
    k_cvtW<<<192, 256, 0, stream>>>(Wih1f, Wih1b, Wihbf);
    k_gru0<<<256, 512, 0, stream>>>(code, Wih0f, Whh0f, bih0f, bhh0f,
                                    Wih0b, Whh0b, bih0b, bhh0b, h0);
    k_gru1f<<<dim3(128, 2), 512, 0, stream>>>(h0, Wihbf,
                                              bih1f, bhh1f, bih1b, bhh1b,
                                              Whh1f, Whh1b, Wfin, partial);
    k_final<<<800, 256, 0, stream>>>(partial, bfin, (float*)d_out);
}

// Round 14
// 643.879 us; speedup vs baseline: 1.1912x; 1.1912x over previous
//
#include <hip/hip_runtime.h>
#include <hip/hip_bf16.h>

#define B_   1024
#define L_   200
#define H_   128
#define BL_  204800   // B_*L_
#define G3_  384

typedef __bf16 bf16x8 __attribute__((ext_vector_type(8)));
typedef __bf16 bf16x4 __attribute__((ext_vector_type(4)));
typedef float  f32x4  __attribute__((ext_vector_type(4)));

__device__ __forceinline__ float sigf(float x) {
    return __builtin_amdgcn_rcpf(1.f + __expf(-x));
}
__device__ __forceinline__ float tanh_fast(float x) {
    float e = __expf(-2.f * x);
    return (1.f - e) * __builtin_amdgcn_rcpf(1.f + e);
}
__device__ __forceinline__ bf16x8 cvt8(float4 a, float4 b) {
    bf16x8 v;
    v[0] = (__bf16)a.x; v[1] = (__bf16)a.y; v[2] = (__bf16)a.z; v[3] = (__bf16)a.w;
    v[4] = (__bf16)b.x; v[5] = (__bf16)b.y; v[6] = (__bf16)b.z; v[7] = (__bf16)b.w;
    return v;
}

// ---------------- K0: sentinel (workspace too small -> distinguishable absmax)
__global__ __launch_bounds__(256) void k_sentinel(float* __restrict__ out, int n) {
    const int i = blockIdx.x * 256 + threadIdx.x;
    if (i < n) out[i] = -5.0f;
}

// ---------------- K1: dec_linear
__global__ __launch_bounds__(256) void k_declin(
    const float* __restrict__ rcv, const float* __restrict__ Wl,
    const float* __restrict__ bl, float* __restrict__ code) {
    __shared__ float rs[4][400];
    const int tid = threadIdx.x;
    const int b0 = blockIdx.x * 4;
    for (int i = tid; i < 1600; i += 256) ((float*)rs)[i] = rcv[(size_t)b0 * 400 + i];
    __syncthreads();
    #pragma unroll
    for (int rep = 0; rep < 2; ++rep) {
        const int j = tid + rep * 256;
        if (j < 400) {
            float a0 = 0.f, a1 = 0.f, a2 = 0.f, a3 = 0.f;
            const float4* wp = (const float4*)(Wl + (size_t)j * 400);
            for (int k = 0; k < 100; ++k) {
                float4 w4 = wp[k];
                const int kk = k * 4;
                a0 += w4.x*rs[0][kk] + w4.y*rs[0][kk+1] + w4.z*rs[0][kk+2] + w4.w*rs[0][kk+3];
                a1 += w4.x*rs[1][kk] + w4.y*rs[1][kk+1] + w4.z*rs[1][kk+2] + w4.w*rs[1][kk+3];
                a2 += w4.x*rs[2][kk] + w4.y*rs[2][kk+1] + w4.z*rs[2][kk+2] + w4.w*rs[2][kk+3];
                a3 += w4.x*rs[3][kk] + w4.y*rs[3][kk+1] + w4.z*rs[3][kk+2] + w4.w*rs[3][kk+3];
            }
            const float bb = bl[j];
            code[(size_t)(b0+0)*400 + j] = a0 + bb;
            code[(size_t)(b0+1)*400 + j] = a1 + bb;
            code[(size_t)(b0+2)*400 + j] = a2 + bb;
            code[(size_t)(b0+3)*400 + j] = a3 + bb;
        }
    }
}

// ---------------- K2: layer0 GRU (r10-proven): tile=8, 8 symmetric waves,
// 256 blocks, one barrier/step, h double-buffered, h0 stores batched via LDS
// stage (flush every 8 steps). MFMA gate chains split 2+2 for latency.
__global__ __launch_bounds__(512, 2) void k_gru0(
    const float* __restrict__ code,
    const float* __restrict__ Wih_f, const float* __restrict__ Whh_f,
    const float* __restrict__ bih_f, const float* __restrict__ bhh_f,
    const float* __restrict__ Wih_b, const float* __restrict__ Whh_b,
    const float* __restrict__ bih_b, const float* __restrict__ bhh_b,
    __bf16* __restrict__ h0) {
    const int dir = blockIdx.y;
    const int b0 = blockIdx.x * 8;
    const float* Wih = dir ? Wih_b : Wih_f;
    const float* Whh = dir ? Whh_b : Whh_f;
    const float* bih = dir ? bih_b : bih_f;
    const float* bhh = dir ? bhh_b : bhh_f;

    const int tid = threadIdx.x;
    const int w = tid >> 6, ln = tid & 63, q = ln >> 4, r16 = ln & 15;
    const int jj = w * 16 + r16;   // this wave's 16 output columns

    __shared__ __bf16 h_bf[2][16][136];      //  8,704 B (rows 8..15 zero pad)
    __shared__ float  code_s[8][400];        // 12,800 B
    __shared__ __bf16 h_st[2][8][8][128];    // 32,768 B stage [grp-par][s][row][col]
                                             // total 54,272 B

    for (int i = tid; i < 8 * 400; i += 512) ((float*)code_s)[i] = code[(size_t)b0 * 400 + i];
    for (int i = tid; i < 2 * 16 * 136; i += 512) ((__bf16*)h_bf)[i] = (__bf16)0.f;

    bf16x8 wfr[3][4];
    const float wr0 = Wih[jj * 2],         wr1 = Wih[jj * 2 + 1];
    const float wz0 = Wih[(jj + 128) * 2], wz1 = Wih[(jj + 128) * 2 + 1];
    const float wn0 = Wih[(jj + 256) * 2], wn1 = Wih[(jj + 256) * 2 + 1];
    const float xbr = bih[jj] + bhh[jj];
    const float xbz = bih[jj + 128] + bhh[jj + 128];
    const float xbn = bih[jj + 256];
    const float bnv = bhh[jj + 256];
    float hreg[4] = {0.f, 0.f, 0.f, 0.f};
    #pragma unroll
    for (int g = 0; g < 3; ++g) {
        const int j = (w + g * 8) * 16 + r16;
        const float* p = Whh + (size_t)j * H_;
        #pragma unroll
        for (int kt = 0; kt < 4; ++kt) {
            float4 x0 = *(const float4*)(p + kt * 32 + q * 8);
            float4 x1 = *(const float4*)(p + kt * 32 + q * 8 + 4);
            wfr[g][kt] = cvt8(x0, x1);
        }
    }
    __syncthreads();

    for (int t = 0; t < L_; ++t) {
        const int cur = t & 1, nxt = cur ^ 1;
        // flush previous 8-step group (stores retire during this step's compute)
        if ((t & 7) == 0 && t > 0) {
            const int g8 = (t >> 3) - 1;
            const int buf = g8 & 1;
            const int p = tid >> 3, inner = tid & 7;     // 64 pairs x 8 threads
            const int s = p >> 3, row = p & 7;
            const int tb = g8 * 8 + s;
            const int l = dir ? (L_ - 1 - tb) : tb;
            const __bf16* src = &h_st[buf][s][row][inner * 16];
            __bf16* dst = &h0[((size_t)(b0 + row) * L_ + l) * 256 + dir * 128 + inner * 16];
            *(bf16x8*)(dst)     = *(const bf16x8*)(src);
            *(bf16x8*)(dst + 8) = *(const bf16x8*)(src + 8);
        }
        const int l = dir ? (L_ - 1 - t) : t;
        bf16x8 af[4];
        #pragma unroll
        for (int kt = 0; kt < 4; ++kt)
            af[kt] = *(const bf16x8*)&h_bf[cur][r16][kt * 32 + q * 8];

        // 2+2 split chains: halves dependent-MFMA depth on the critical path
        f32x4 arA = {0.f,0.f,0.f,0.f}, arB = {0.f,0.f,0.f,0.f};
        f32x4 azA = {0.f,0.f,0.f,0.f}, azB = {0.f,0.f,0.f,0.f};
        f32x4 anA = {0.f,0.f,0.f,0.f}, anB = {0.f,0.f,0.f,0.f};
        arA = __builtin_amdgcn_mfma_f32_16x16x32_bf16(af[0], wfr[0][0], arA, 0, 0, 0);
        azA = __builtin_amdgcn_mfma_f32_16x16x32_bf16(af[0], wfr[1][0], azA, 0, 0, 0);
        anA = __builtin_amdgcn_mfma_f32_16x16x32_bf16(af[0], wfr[2][0], anA, 0, 0, 0);
        arB = __builtin_amdgcn_mfma_f32_16x16x32_bf16(af[2], wfr[0][2], arB, 0, 0, 0);
        azB = __builtin_amdgcn_mfma_f32_16x16x32_bf16(af[2], wfr[1][2], azB, 0, 0, 0);
        anB = __builtin_amdgcn_mfma_f32_16x16x32_bf16(af[2], wfr[2][2], anB, 0, 0, 0);
        arA = __builtin_amdgcn_mfma_f32_16x16x32_bf16(af[1], wfr[0][1], arA, 0, 0, 0);
        azA = __builtin_amdgcn_mfma_f32_16x16x32_bf16(af[1], wfr[1][1], azA, 0, 0, 0);
        anA = __builtin_amdgcn_mfma_f32_16x16x32_bf16(af[1], wfr[2][1], anA, 0, 0, 0);
        arB = __builtin_amdgcn_mfma_f32_16x16x32_bf16(af[3], wfr[0][3], arB, 0, 0, 0);
        azB = __builtin_amdgcn_mfma_f32_16x16x32_bf16(af[3], wfr[1][3], azB, 0, 0, 0);
        anB = __builtin_amdgcn_mfma_f32_16x16x32_bf16(af[3], wfr[2][3], anB, 0, 0, 0);
        const f32x4 ar = arA + arB, az = azA + azB, an = anA + anB;

        if (q < 2) {   // real rows 0..7 (MFMA C-layout ties m to q*4+reg)
            #pragma unroll
            for (int reg = 0; reg < 4; ++reg) {
                const int m = q * 4 + reg;
                const float c0 = code_s[m][l * 2], c1 = code_s[m][l * 2 + 1];
                const float r = sigf(c0 * wr0 + c1 * wr1 + xbr + ar[reg]);
                const float z = sigf(c0 * wz0 + c1 * wz1 + xbz + az[reg]);
                const float n = tanh_fast(c0 * wn0 + c1 * wn1 + xbn + r * (an[reg] + bnv));
                const float hv = n + z * (hreg[reg] - n);
                hreg[reg] = hv;
                h_bf[nxt][m][jj] = (__bf16)hv;
                h_st[(t >> 3) & 1][t & 7][m][jj] = (__bf16)hv;
            }
        }
        __syncthreads();   // single barrier: h[nxt] + stage visible
    }
    {   // final flush: group 24 (t=192..199), buf = 24&1 = 0
        const int p = tid >> 3, inner = tid & 7;
        const int s = p >> 3, row = p & 7;
        const int tb = 192 + s;
        const int l = dir ? (L_ - 1 - tb) : tb;
        const __bf16* src = &h_st[0][s][row][inner * 16];
        __bf16* dst = &h0[((size_t)(b0 + row) * L_ + l) * 256 + dir * 128 + inner * 16];
        *(bf16x8*)(dst)     = *(const bf16x8*)(src);
        *(bf16x8*)(dst + 8) = *(const bf16x8*)(src + 8);
    }
}

// ---------------- K3: convert Wih1 (both dirs) fp32 -> bf16  [2][384][256]
__global__ __launch_bounds__(256) void k_cvtW(
    const float* __restrict__ Wfp, const float* __restrict__ Wbp,
    __bf16* __restrict__ out) {
    const int j = blockIdx.x * 256 + threadIdx.x;
    const int base = j * 4;
    const int dir = base >= 98304;
    const int idx = dir ? base - 98304 : base;
    float4 v = *(const float4*)((dir ? Wbp : Wfp) + idx);
    bf16x4 o;
    o[0] = (__bf16)v.x; o[1] = (__bf16)v.y; o[2] = (__bf16)v.z; o[3] = (__bf16)v.w;
    *(bf16x4*)&out[base] = o;
}

// ---------------- K4: layer1 GRU (r12 structure): tile=8, 8 waves, Wih1
// B-frags register-resident, k8-outer GEMM, A-chunk double-buffered with
// register prefetch parked at s==2, chunk = 4 steps, one barrier per step.
// MFMA gate chains split 2+2 for latency.
__global__ __launch_bounds__(512, 2) void k_gru1f(
    const __bf16* __restrict__ h0,       // [B][L][256]
    const __bf16* __restrict__ Wihbf,    // [2][384][256] bf16
    const float* __restrict__ bih_f, const float* __restrict__ bhh_f,
    const float* __restrict__ bih_b, const float* __restrict__ bhh_b,
    const float* __restrict__ Whh_f, const float* __restrict__ Whh_b,
    const float* __restrict__ Wfin,
    float* __restrict__ partial) {
    const int dir = blockIdx.y;
    const int b0 = blockIdx.x * 8;
    const float* Whh = dir ? Whh_b : Whh_f;
    const float* bih = dir ? bih_b : bih_f;
    const float* bhh = dir ? bhh_b : bhh_f;
    const __bf16* Wb = Wihbf + (size_t)dir * 384 * 256;

    const int tid = threadIdx.x;
    const int w = tid >> 6, ln = tid & 63, q = ln >> 4, r16 = ln & 15;
    const int jj = w * 16 + r16;   // this wave's 16 recurrence columns

    __shared__ __bf16 xa[2][32][264];    // 33,792 B  A-chunk dbuf (rows = s*8+bt)
    __shared__ __bf16 xgT[384][36];      // 27,648 B  [col][chunk row (32) + pad]
    __shared__ __bf16 h_bf[2][16][136];  //  8,704 B  (rows 8..15 zero pad)
    __shared__ float  wacc[2][8][8];     //    512 B  -> total 70,656 B

    for (int i = tid; i < 2 * 16 * 136; i += 512) ((__bf16*)h_bf)[i] = (__bf16)0.f;

    bf16x8 wfr[3][4];
    bf16x8 wB[3][8];                      // register-resident Wih1 B-frags
    const float xbr = bih[jj] + bhh[jj];
    const float xbz = bih[jj + 128] + bhh[jj + 128];
    const float xbn = bih[jj + 256];
    const float bnv = bhh[jj + 256];
    const float wfv = Wfin[dir * 128 + jj];
    float hreg[4] = {0.f, 0.f, 0.f, 0.f};
    #pragma unroll
    for (int g = 0; g < 3; ++g) {
        const int j = (w + g * 8) * 16 + r16;
        const float* p = Whh + (size_t)j * H_;
        #pragma unroll
        for (int kt = 0; kt < 4; ++kt) {
            float4 x0 = *(const float4*)(p + kt * 32 + q * 8);
            float4 x1 = *(const float4*)(p + kt * 32 + q * 8 + 4);
            wfr[g][kt] = cvt8(x0, x1);
        }
    }
    #pragma unroll
    for (int n = 0; n < 3; ++n) {
        const int ct = w * 3 + n;
        const __bf16* wp = Wb + (size_t)(ct * 16 + r16) * 256 + q * 8;
        #pragma unroll
        for (int k8 = 0; k8 < 8; ++k8)
            wB[n][k8] = *(const bf16x8*)(wp + k8 * 32);
    }
    // prologue: stage chunk 0 into xa[0]
    {
        const int r = tid >> 4, seg = tid & 15;       // 32 rows x 16 threads
        const int s = r >> 3, bt = r & 7;
        const int l = dir ? (L_ - 1 - s) : s;         // t = s
        const __bf16* src = h0 + ((size_t)(b0 + bt) * L_ + l) * 256 + seg * 16;
        *(bf16x8*)&xa[0][r][seg * 16]     = *(const bf16x8*)(src);
        *(bf16x8*)&xa[0][r][seg * 16 + 8] = *(const bf16x8*)(src + 8);
    }
    __syncthreads();

    int gstep = 0;
    for (int c = 0; c < 50; ++c) {
        const int cb = c & 1, nb = cb ^ 1;
        // ---- issue prefetch loads for chunk c+1 (hidden under GEMM + 3 steps)
        bf16x8 pf0, pf1;
        const bool pv = (c + 1 < 50);
        const int prr = tid >> 4, prs = tid & 15;
        if (pv) {
            const int s = prr >> 3, bt = prr & 7;
            const int t = (c + 1) * 4 + s;
            const int l = dir ? (L_ - 1 - t) : t;
            const __bf16* src = h0 + ((size_t)(b0 + bt) * L_ + l) * 256 + prs * 16;
            pf0 = *(const bf16x8*)(src);
            pf1 = *(const bf16x8*)(src + 8);
        }

        // ---- chunk GEMM: xg[32 x 384] = xa[cb] @ Wih1^T; A read once per k8,
        // reused across the wave's 3 register-resident col-tiles.
        {
            f32x4 acc[3][2];
            #pragma unroll
            for (int n = 0; n < 3; ++n)
                #pragma unroll
                for (int mt = 0; mt < 2; ++mt) {
                    acc[n][mt][0]=0.f; acc[n][mt][1]=0.f;
                    acc[n][mt][2]=0.f; acc[n][mt][3]=0.f;
                }
            #pragma unroll
            for (int k8 = 0; k8 < 8; ++k8) {
                const bf16x8 a0 = *(const bf16x8*)&xa[cb][r16][k8 * 32 + q * 8];
                const bf16x8 a1 = *(const bf16x8*)&xa[cb][16 + r16][k8 * 32 + q * 8];
                #pragma unroll
                for (int n = 0; n < 3; ++n) {
                    acc[n][0] = __builtin_amdgcn_mfma_f32_16x16x32_bf16(a0, wB[n][k8], acc[n][0], 0, 0, 0);
                    acc[n][1] = __builtin_amdgcn_mfma_f32_16x16x32_bf16(a1, wB[n][k8], acc[n][1], 0, 0, 0);
                }
            }
            #pragma unroll
            for (int n = 0; n < 3; ++n) {
                const int ct = w * 3 + n;
                #pragma unroll
                for (int mt = 0; mt < 2; ++mt) {
                    bf16x4 o;
                    o[0] = (__bf16)acc[n][mt][0]; o[1] = (__bf16)acc[n][mt][1];
                    o[2] = (__bf16)acc[n][mt][2]; o[3] = (__bf16)acc[n][mt][3];
                    *(bf16x4*)&xgT[ct * 16 + r16][mt * 16 + q * 4] = o;
                }
            }
        }
        __syncthreads();   // xgT ready

        // ---- 4 recurrent steps, one barrier each
        for (int s = 0; s < 4; ++s, ++gstep) {
            const int cur = gstep & 1, nxt = cur ^ 1;
            const int par = s & 1;
            const int t = c * 4 + s;
            const int l = dir ? (L_ - 1 - t) : t;

            bf16x8 af[4];
            #pragma unroll
            for (int kt = 0; kt < 4; ++kt)
                af[kt] = *(const bf16x8*)&h_bf[cur][r16][kt * 32 + q * 8];

            // 2+2 split chains
            f32x4 arA = {0.f,0.f,0.f,0.f}, arB = {0.f,0.f,0.f,0.f};
            f32x4 azA = {0.f,0.f,0.f,0.f}, azB = {0.f,0.f,0.f,0.f};
            f32x4 anA = {0.f,0.f,0.f,0.f}, anB = {0.f,0.f,0.f,0.f};
            arA = __builtin_amdgcn_mfma_f32_16x16x32_bf16(af[0], wfr[0][0], arA, 0, 0, 0);
            azA = __builtin_amdgcn_mfma_f32_16x16x32_bf16(af[0], wfr[1][0], azA, 0, 0, 0);
            anA = __builtin_amdgcn_mfma_f32_16x16x32_bf16(af[0], wfr[2][0], anA, 0, 0, 0);
            arB = __builtin_amdgcn_mfma_f32_16x16x32_bf16(af[2], wfr[0][2], arB, 0, 0, 0);
            azB = __builtin_amdgcn_mfma_f32_16x16x32_bf16(af[2], wfr[1][2], azB, 0, 0, 0);
            anB = __builtin_amdgcn_mfma_f32_16x16x32_bf16(af[2], wfr[2][2], anB, 0, 0, 0);
            arA = __builtin_amdgcn_mfma_f32_16x16x32_bf16(af[1], wfr[0][1], arA, 0, 0, 0);
            azA = __builtin_amdgcn_mfma_f32_16x16x32_bf16(af[1], wfr[1][1], azA, 0, 0, 0);
            anA = __builtin_amdgcn_mfma_f32_16x16x32_bf16(af[1], wfr[2][1], anA, 0, 0, 0);
            arB = __builtin_amdgcn_mfma_f32_16x16x32_bf16(af[3], wfr[0][3], arB, 0, 0, 0);
            azB = __builtin_amdgcn_mfma_f32_16x16x32_bf16(af[3], wfr[1][3], azB, 0, 0, 0);
            anB = __builtin_amdgcn_mfma_f32_16x16x32_bf16(af[3], wfr[2][3], anB, 0, 0, 0);
            const f32x4 ar = arA + arB, az = azA + azB, an = anA + anB;

            if (q < 2) {   // real rows 0..7
                bf16x4 xr4 = *(const bf16x4*)&xgT[jj      ][s * 8 + q * 4];
                bf16x4 xz4 = *(const bf16x4*)&xgT[jj + 128][s * 8 + q * 4];
                bf16x4 xn4 = *(const bf16x4*)&xgT[jj + 256][s * 8 + q * 4];
                #pragma unroll
                for (int reg = 0; reg < 4; ++reg) {
                    const int m = q * 4 + reg;
                    const float r = sigf((float)xr4[reg] + xbr + ar[reg]);
                    const float z = sigf((float)xz4[reg] + xbz + az[reg]);
                    const float n = tanh_fast((float)xn4[reg] + xbn + r * (an[reg] + bnv));
                    const float hv = n + z * (hreg[reg] - n);
                    hreg[reg] = hv;
                    h_bf[nxt][m][jj] = (__bf16)hv;
                }
                // fused final-linear partial dot (this wave's 16-col slice)
                #pragma unroll
                for (int reg = 0; reg < 4; ++reg) {
                    float v = hreg[reg] * wfv;
                    v += __shfl_xor(v, 1); v += __shfl_xor(v, 2);
                    v += __shfl_xor(v, 4); v += __shfl_xor(v, 8);
                    if (r16 == 0) wacc[par][w][q * 4 + reg] = v;
                }
            }
            // park prefetched chunk c+1 into xa[nb]; published by this barrier
            if (pv && s == 2) {
                *(bf16x8*)&xa[nb][prr][prs * 16]     = pf0;
                *(bf16x8*)&xa[nb][prr][prs * 16 + 8] = pf1;
            }
            __syncthreads();   // single barrier: h[nxt] + wacc[par] (+ xa park) visible
            if (tid < 8) {     // tiny store, drains during next interval
                float v = 0.f;
                #pragma unroll
                for (int ww = 0; ww < 8; ++ww) v += wacc[par][ww][tid];
                partial[(size_t)dir * BL_ + (size_t)(b0 + tid) * L_ + l] = v;
            }
        }
    }
}

// ---------------- K5: out = sigmoid(pf + pb + bf)
__global__ __launch_bounds__(256) void k_final(
    const float* __restrict__ partial, const float* __restrict__ bfp,
    float* __restrict__ out) {
    const int i = blockIdx.x * 256 + threadIdx.x;
    if (i < BL_) out[i] = sigf(partial[i] + partial[BL_ + i] + bfp[0]);
}

extern "C" void kernel_launch(void* const* d_in, const int* in_sizes, int n_in,
                              void* d_out, int out_size, void* d_ws, size_t ws_size,
                              hipStream_t stream) {
    const float* rcv   = (const float*)d_in[0];
    const float* Wl    = (const float*)d_in[1];
    const float* bl    = (const float*)d_in[2];
    const float* Wih0f = (const float*)d_in[3];
    const float* Whh0f = (const float*)d_in[4];
    const float* bih0f = (const float*)d_in[5];
    const float* bhh0f = (const float*)d_in[6];
    const float* Wih0b = (const float*)d_in[7];
    const float* Whh0b = (const float*)d_in[8];
    const float* bih0b = (const float*)d_in[9];
    const float* bhh0b = (const float*)d_in[10];
    const float* Wih1f = (const float*)d_in[11];
    const float* Whh1f = (const float*)d_in[12];
    const float* bih1f = (const float*)d_in[13];
    const float* bhh1f = (const float*)d_in[14];
    const float* Wih1b = (const float*)d_in[15];
    const float* Whh1b = (const float*)d_in[16];
    const float* bih1b = (const float*)d_in[17];
    const float* bhh1b = (const float*)d_in[18];
    const float* Wfin  = (const float*)d_in[19];
    const float* bfin  = (const float*)d_in[20];

    const size_t OFF_CODE = 0;                     // 1,638,400 B
    const size_t OFF_PART = 1638400;               // 1,638,400 B
    const size_t OFF_H0   = 3276800;               // 104,857,600 B
    const size_t OFF_WBF  = 108134400;             //     393,216 B
    const size_t WS_NEEDED = 108527616;            // ~103.5 MB total

    if (ws_size < WS_NEEDED) {
        k_sentinel<<<(out_size + 255) / 256, 256, 0, stream>>>((float*)d_out, out_size);
        return;
    }

    char* ws = (char*)d_ws;
    float*  code    = (float*)(ws + OFF_CODE);
    float*  partial = (float*)(ws + OFF_PART);
    __bf16* h0      = (__bf16*)(ws + OFF_H0);
    __bf16* Wihbf   = (__bf16*)(ws + OFF_WBF);

    k_declin<<<256, 256, 0, stream>>>(rcv, Wl, bl, code);
    k_cvtW<<<192, 256, 0, stream>>>(Wih1f, Wih1b, Wihbf);
    k_gru0<<<dim3(128, 2), 512, 0, stream>>>(code, Wih0f, Whh0f, bih0f, bhh0f,
                                             Wih0b, Whh0b, bih0b, bhh0b, h0);
    k_gru1f<<<dim3(128, 2), 512, 0, stream>>>(h0, Wihbf,
                                              bih1f, bhh1f, bih1b, bhh1b,
                                              Whh1f, Whh1b, Wfin, partial);
    k_final<<<800, 256, 0, stream>>>(partial, bfin, (float*)d_out);
}

// Round 15
// 607.114 us; speedup vs baseline: 1.2633x; 1.0606x over previous
//
#include <hip/hip_runtime.h>
#include <hip/hip_bf16.h>

#define B_   1024
#define L_   200
#define H_   128
#define BL_  204800   // B_*L_
#define G3_  384

typedef __bf16 bf16x8 __attribute__((ext_vector_type(8)));
typedef __bf16 bf16x4 __attribute__((ext_vector_type(4)));
typedef float  f32x4  __attribute__((ext_vector_type(4)));

__device__ __forceinline__ float sigf(float x) {
    return __builtin_amdgcn_rcpf(1.f + __expf(-x));
}
__device__ __forceinline__ float tanh_fast(float x) {
    float e = __expf(-2.f * x);
    return (1.f - e) * __builtin_amdgcn_rcpf(1.f + e);
}
__device__ __forceinline__ bf16x8 cvt8(float4 a, float4 b) {
    bf16x8 v;
    v[0] = (__bf16)a.x; v[1] = (__bf16)a.y; v[2] = (__bf16)a.z; v[3] = (__bf16)a.w;
    v[4] = (__bf16)b.x; v[5] = (__bf16)b.y; v[6] = (__bf16)b.z; v[7] = (__bf16)b.w;
    return v;
}

// ---------------- K0: sentinel (workspace too small -> distinguishable absmax)
__global__ __launch_bounds__(256) void k_sentinel(float* __restrict__ out, int n) {
    const int i = blockIdx.x * 256 + threadIdx.x;
    if (i < n) out[i] = -5.0f;
}

// ---------------- K1: dec_linear
__global__ __launch_bounds__(256) void k_declin(
    const float* __restrict__ rcv, const float* __restrict__ Wl,
    const float* __restrict__ bl, float* __restrict__ code) {
    __shared__ float rs[4][400];
    const int tid = threadIdx.x;
    const int b0 = blockIdx.x * 4;
    for (int i = tid; i < 1600; i += 256) ((float*)rs)[i] = rcv[(size_t)b0 * 400 + i];
    __syncthreads();
    #pragma unroll
    for (int rep = 0; rep < 2; ++rep) {
        const int j = tid + rep * 256;
        if (j < 400) {
            float a0 = 0.f, a1 = 0.f, a2 = 0.f, a3 = 0.f;
            const float4* wp = (const float4*)(Wl + (size_t)j * 400);
            for (int k = 0; k < 100; ++k) {
                float4 w4 = wp[k];
                const int kk = k * 4;
                a0 += w4.x*rs[0][kk] + w4.y*rs[0][kk+1] + w4.z*rs[0][kk+2] + w4.w*rs[0][kk+3];
                a1 += w4.x*rs[1][kk] + w4.y*rs[1][kk+1] + w4.z*rs[1][kk+2] + w4.w*rs[1][kk+3];
                a2 += w4.x*rs[2][kk] + w4.y*rs[2][kk+1] + w4.z*rs[2][kk+2] + w4.w*rs[2][kk+3];
                a3 += w4.x*rs[3][kk] + w4.y*rs[3][kk+1] + w4.z*rs[3][kk+2] + w4.w*rs[3][kk+3];
            }
            const float bb = bl[j];
            code[(size_t)(b0+0)*400 + j] = a0 + bb;
            code[(size_t)(b0+1)*400 + j] = a1 + bb;
            code[(size_t)(b0+2)*400 + j] = a2 + bb;
            code[(size_t)(b0+3)*400 + j] = a3 + bb;
        }
    }
}

// ---------------- K2: layer0 GRU (r12-exact): tile=8, 8 symmetric waves,
// 256 blocks, one barrier/step, h double-buffered, h0 stores batched via LDS
// stage (flush every 8 steps).
__global__ __launch_bounds__(512, 2) void k_gru0(
    const float* __restrict__ code,
    const float* __restrict__ Wih_f, const float* __restrict__ Whh_f,
    const float* __restrict__ bih_f, const float* __restrict__ bhh_f,
    const float* __restrict__ Wih_b, const float* __restrict__ Whh_b,
    const float* __restrict__ bih_b, const float* __restrict__ bhh_b,
    __bf16* __restrict__ h0) {
    const int dir = blockIdx.y;
    const int b0 = blockIdx.x * 8;
    const float* Wih = dir ? Wih_b : Wih_f;
    const float* Whh = dir ? Whh_b : Whh_f;
    const float* bih = dir ? bih_b : bih_f;
    const float* bhh = dir ? bhh_b : bhh_f;

    const int tid = threadIdx.x;
    const int w = tid >> 6, ln = tid & 63, q = ln >> 4, r16 = ln & 15;
    const int jj = w * 16 + r16;   // this wave's 16 output columns

    __shared__ __bf16 h_bf[2][16][136];      //  8,704 B (rows 8..15 zero pad)
    __shared__ float  code_s[8][400];        // 12,800 B
    __shared__ __bf16 h_st[2][8][8][128];    // 32,768 B stage [grp-par][s][row][col]
                                             // total 54,272 B

    for (int i = tid; i < 8 * 400; i += 512) ((float*)code_s)[i] = code[(size_t)b0 * 400 + i];
    for (int i = tid; i < 2 * 16 * 136; i += 512) ((__bf16*)h_bf)[i] = (__bf16)0.f;

    bf16x8 wfr[3][4];
    const float wr0 = Wih[jj * 2],         wr1 = Wih[jj * 2 + 1];
    const float wz0 = Wih[(jj + 128) * 2], wz1 = Wih[(jj + 128) * 2 + 1];
    const float wn0 = Wih[(jj + 256) * 2], wn1 = Wih[(jj + 256) * 2 + 1];
    const float xbr = bih[jj] + bhh[jj];
    const float xbz = bih[jj + 128] + bhh[jj + 128];
    const float xbn = bih[jj + 256];
    const float bnv = bhh[jj + 256];
    float hreg[4] = {0.f, 0.f, 0.f, 0.f};
    #pragma unroll
    for (int g = 0; g < 3; ++g) {
        const int j = (w + g * 8) * 16 + r16;
        const float* p = Whh + (size_t)j * H_;
        #pragma unroll
        for (int kt = 0; kt < 4; ++kt) {
            float4 x0 = *(const float4*)(p + kt * 32 + q * 8);
            float4 x1 = *(const float4*)(p + kt * 32 + q * 8 + 4);
            wfr[g][kt] = cvt8(x0, x1);
        }
    }
    __syncthreads();

    for (int t = 0; t < L_; ++t) {
        const int cur = t & 1, nxt = cur ^ 1;
        // flush previous 8-step group (stores retire during this step's compute)
        if ((t & 7) == 0 && t > 0) {
            const int g8 = (t >> 3) - 1;
            const int buf = g8 & 1;
            const int p = tid >> 3, inner = tid & 7;     // 64 pairs x 8 threads
            const int s = p >> 3, row = p & 7;
            const int tb = g8 * 8 + s;
            const int l = dir ? (L_ - 1 - tb) : tb;
            const __bf16* src = &h_st[buf][s][row][inner * 16];
            __bf16* dst = &h0[((size_t)(b0 + row) * L_ + l) * 256 + dir * 128 + inner * 16];
            *(bf16x8*)(dst)     = *(const bf16x8*)(src);
            *(bf16x8*)(dst + 8) = *(const bf16x8*)(src + 8);
        }
        const int l = dir ? (L_ - 1 - t) : t;
        bf16x8 af[4];
        #pragma unroll
        for (int kt = 0; kt < 4; ++kt)
            af[kt] = *(const bf16x8*)&h_bf[cur][r16][kt * 32 + q * 8];

        f32x4 ar = {0.f,0.f,0.f,0.f}, az = {0.f,0.f,0.f,0.f}, an = {0.f,0.f,0.f,0.f};
        #pragma unroll
        for (int kt = 0; kt < 4; ++kt) {
            ar = __builtin_amdgcn_mfma_f32_16x16x32_bf16(af[kt], wfr[0][kt], ar, 0, 0, 0);
            az = __builtin_amdgcn_mfma_f32_16x16x32_bf16(af[kt], wfr[1][kt], az, 0, 0, 0);
            an = __builtin_amdgcn_mfma_f32_16x16x32_bf16(af[kt], wfr[2][kt], an, 0, 0, 0);
        }
        if (q < 2) {   // real rows 0..7 (MFMA C-layout ties m to q*4+reg)
            #pragma unroll
            for (int reg = 0; reg < 4; ++reg) {
                const int m = q * 4 + reg;
                const float c0 = code_s[m][l * 2], c1 = code_s[m][l * 2 + 1];
                const float r = sigf(c0 * wr0 + c1 * wr1 + xbr + ar[reg]);
                const float z = sigf(c0 * wz0 + c1 * wz1 + xbz + az[reg]);
                const float n = tanh_fast(c0 * wn0 + c1 * wn1 + xbn + r * (an[reg] + bnv));
                const float hv = n + z * (hreg[reg] - n);
                hreg[reg] = hv;
                h_bf[nxt][m][jj] = (__bf16)hv;
                h_st[(t >> 3) & 1][t & 7][m][jj] = (__bf16)hv;
            }
        }
        __syncthreads();   // single barrier: h[nxt] + stage visible
    }
    {   // final flush: group 24 (t=192..199), buf = 24&1 = 0
        const int p = tid >> 3, inner = tid & 7;
        const int s = p >> 3, row = p & 7;
        const int tb = 192 + s;
        const int l = dir ? (L_ - 1 - tb) : tb;
        const __bf16* src = &h_st[0][s][row][inner * 16];
        __bf16* dst = &h0[((size_t)(b0 + row) * L_ + l) * 256 + dir * 128 + inner * 16];
        *(bf16x8*)(dst)     = *(const bf16x8*)(src);
        *(bf16x8*)(dst + 8) = *(const bf16x8*)(src + 8);
    }
}

// ---------------- K3: convert Wih1 (both dirs) fp32 -> bf16  [2][384][256]
__global__ __launch_bounds__(256) void k_cvtW(
    const float* __restrict__ Wfp, const float* __restrict__ Wbp,
    __bf16* __restrict__ out) {
    const int j = blockIdx.x * 256 + threadIdx.x;
    const int base = j * 4;
    const int dir = base >= 98304;
    const int idx = dir ? base - 98304 : base;
    float4 v = *(const float4*)((dir ? Wbp : Wfp) + idx);
    bf16x4 o;
    o[0] = (__bf16)v.x; o[1] = (__bf16)v.y; o[2] = (__bf16)v.z; o[3] = (__bf16)v.w;
    *(bf16x4*)&out[base] = o;
}

// ---------------- K4: layer1 GRU — xg kept ENTIRELY IN REGISTERS.
// Wave w's GEMM computes n-tiles {w, w+8, w+16} = cols {jj, jj+128, jj+256}:
// exactly its own recurrence gate columns. Rows: even steps (s=0,2) are the
// lane's own C-layout quadrant (mt=s/2); odd steps come from quadrants 2..3
// via __shfl_xor(.,32). Eliminates xgT LDS (27.6 KB), its store/load traffic,
// and the per-chunk xgT barrier (4 barriers per 4 steps instead of 5).
// A-chunk double-buffered with register prefetch parked at s==2.
__global__ __launch_bounds__(512, 2) void k_gru1f(
    const __bf16* __restrict__ h0,       // [B][L][256]
    const __bf16* __restrict__ Wihbf,    // [2][384][256] bf16
    const float* __restrict__ bih_f, const float* __restrict__ bhh_f,
    const float* __restrict__ bih_b, const float* __restrict__ bhh_b,
    const float* __restrict__ Whh_f, const float* __restrict__ Whh_b,
    const float* __restrict__ Wfin,
    float* __restrict__ partial) {
    const int dir = blockIdx.y;
    const int b0 = blockIdx.x * 8;
    const float* Whh = dir ? Whh_b : Whh_f;
    const float* bih = dir ? bih_b : bih_f;
    const float* bhh = dir ? bhh_b : bhh_f;
    const __bf16* Wb = Wihbf + (size_t)dir * 384 * 256;

    const int tid = threadIdx.x;
    const int w = tid >> 6, ln = tid & 63, q = ln >> 4, r16 = ln & 15;
    const int jj = w * 16 + r16;   // this wave's 16 recurrence columns

    __shared__ __bf16 xa[2][32][264];    // 33,792 B  A-chunk dbuf (rows = s*8+bt)
    __shared__ __bf16 h_bf[2][16][136];  //  8,704 B  (rows 8..15 zero pad)
    __shared__ float  wacc[2][8][8];     //    512 B  -> total 43,008 B

    for (int i = tid; i < 2 * 16 * 136; i += 512) ((__bf16*)h_bf)[i] = (__bf16)0.f;

    bf16x8 wfr[3][4];
    bf16x8 wB[3][8];                      // register-resident Wih1 B-frags
    const float xbr = bih[jj] + bhh[jj];
    const float xbz = bih[jj + 128] + bhh[jj + 128];
    const float xbn = bih[jj + 256];
    const float bnv = bhh[jj + 256];
    const float wfv = Wfin[dir * 128 + jj];
    float hreg[4] = {0.f, 0.f, 0.f, 0.f};
    #pragma unroll
    for (int g = 0; g < 3; ++g) {
        const int j = (w + g * 8) * 16 + r16;
        const float* p = Whh + (size_t)j * H_;
        #pragma unroll
        for (int kt = 0; kt < 4; ++kt) {
            float4 x0 = *(const float4*)(p + kt * 32 + q * 8);
            float4 x1 = *(const float4*)(p + kt * 32 + q * 8 + 4);
            wfr[g][kt] = cvt8(x0, x1);
        }
    }
    #pragma unroll
    for (int n = 0; n < 3; ++n) {
        const int ct = w + n * 8;        // tile ct -> cols jj + n*128
        const __bf16* wp = Wb + (size_t)(ct * 16 + r16) * 256 + q * 8;
        #pragma unroll
        for (int k8 = 0; k8 < 8; ++k8)
            wB[n][k8] = *(const bf16x8*)(wp + k8 * 32);
    }
    // prologue: stage chunk 0 into xa[0]
    {
        const int r = tid >> 4, seg = tid & 15;       // 32 rows x 16 threads
        const int s = r >> 3, bt = r & 7;
        const int l = dir ? (L_ - 1 - s) : s;         // t = s
        const __bf16* src = h0 + ((size_t)(b0 + bt) * L_ + l) * 256 + seg * 16;
        *(bf16x8*)&xa[0][r][seg * 16]     = *(const bf16x8*)(src);
        *(bf16x8*)&xa[0][r][seg * 16 + 8] = *(const bf16x8*)(src + 8);
    }
    __syncthreads();

    for (int c = 0; c < 50; ++c) {
        const int cb = c & 1, nb = cb ^ 1;
        // ---- issue prefetch loads for chunk c+1 (hidden under GEMM + 3 steps)
        bf16x8 pf0, pf1;
        const bool pv = (c + 1 < 50);
        const int prr = tid >> 4, prs = tid & 15;
        if (pv) {
            const int s = prr >> 3, bt = prr & 7;
            const int t = (c + 1) * 4 + s;
            const int l = dir ? (L_ - 1 - t) : t;
            const __bf16* src = h0 + ((size_t)(b0 + bt) * L_ + l) * 256 + prs * 16;
            pf0 = *(const bf16x8*)(src);
            pf1 = *(const bf16x8*)(src + 8);
        }

        // ---- chunk GEMM into persistent registers: accg[n][mt] holds
        // xg[row = mt*16 + q*4 + reg][col = jj + n*128] (fp32, no LDS round trip)
        f32x4 accg[3][2];
        #pragma unroll
        for (int n = 0; n < 3; ++n)
            #pragma unroll
            for (int mt = 0; mt < 2; ++mt) {
                accg[n][mt][0]=0.f; accg[n][mt][1]=0.f;
                accg[n][mt][2]=0.f; accg[n][mt][3]=0.f;
            }
        #pragma unroll
        for (int k8 = 0; k8 < 8; ++k8) {
            const bf16x8 a0 = *(const bf16x8*)&xa[cb][r16][k8 * 32 + q * 8];
            const bf16x8 a1 = *(const bf16x8*)&xa[cb][16 + r16][k8 * 32 + q * 8];
            #pragma unroll
            for (int n = 0; n < 3; ++n) {
                accg[n][0] = __builtin_amdgcn_mfma_f32_16x16x32_bf16(a0, wB[n][k8], accg[n][0], 0, 0, 0);
                accg[n][1] = __builtin_amdgcn_mfma_f32_16x16x32_bf16(a1, wB[n][k8], accg[n][1], 0, 0, 0);
            }
        }
        // NO barrier: GEMM wrote no LDS; step 0's h_bf read is protected by the
        // previous step's barrier.

        // ---- 4 recurrent steps, one barrier each
        #pragma unroll
        for (int s = 0; s < 4; ++s) {
            const int cur = s & 1, nxt = cur ^ 1;   // gstep = 4c+s, 4c even
            const int par = s & 1;
            const int t = c * 4 + s;
            const int l = dir ? (L_ - 1 - t) : t;
            const int mt = s >> 1;

            bf16x8 af[4];
            #pragma unroll
            for (int kt = 0; kt < 4; ++kt)
                af[kt] = *(const bf16x8*)&h_bf[cur][r16][kt * 32 + q * 8];

            f32x4 ar = {0.f,0.f,0.f,0.f}, az = {0.f,0.f,0.f,0.f}, an = {0.f,0.f,0.f,0.f};
            #pragma unroll
            for (int kt = 0; kt < 4; ++kt) {
                ar = __builtin_amdgcn_mfma_f32_16x16x32_bf16(af[kt], wfr[0][kt], ar, 0, 0, 0);
                az = __builtin_amdgcn_mfma_f32_16x16x32_bf16(af[kt], wfr[1][kt], az, 0, 0, 0);
                an = __builtin_amdgcn_mfma_f32_16x16x32_bf16(af[kt], wfr[2][kt], an, 0, 0, 0);
            }

            // gate inputs from registers: step rows s*8+m. Even s: own quadrant
            // (tile rows 0..7). Odd s: tile rows 8..15 live in lanes q+2 -> shfl.
            float xr_[4], xz_[4], xn_[4];
            #pragma unroll
            for (int reg = 0; reg < 4; ++reg) {
                float v0 = accg[0][mt][reg];
                float v1 = accg[1][mt][reg];
                float v2 = accg[2][mt][reg];
                if (s & 1) {
                    v0 = __shfl_xor(v0, 32);
                    v1 = __shfl_xor(v1, 32);
                    v2 = __shfl_xor(v2, 32);
                }
                xr_[reg] = v0; xz_[reg] = v1; xn_[reg] = v2;
            }

            if (q < 2) {   // real rows 0..7
                #pragma unroll
                for (int reg = 0; reg < 4; ++reg) {
                    const int m = q * 4 + reg;
                    const float r = sigf(xr_[reg] + xbr + ar[reg]);
                    const float z = sigf(xz_[reg] + xbz + az[reg]);
                    const float n = tanh_fast(xn_[reg] + xbn + r * (an[reg] + bnv));
                    const float hv = n + z * (hreg[reg] - n);
                    hreg[reg] = hv;
                    h_bf[nxt][m][jj] = (__bf16)hv;
                }
                // fused final-linear partial dot (this wave's 16-col slice)
                #pragma unroll
                for (int reg = 0; reg < 4; ++reg) {
                    float v = hreg[reg] * wfv;
                    v += __shfl_xor(v, 1); v += __shfl_xor(v, 2);
                    v += __shfl_xor(v, 4); v += __shfl_xor(v, 8);
                    if (r16 == 0) wacc[par][w][q * 4 + reg] = v;
                }
            }
            // park prefetched chunk c+1 into xa[nb]; published by this barrier
            if (pv && s == 2) {
                *(bf16x8*)&xa[nb][prr][prs * 16]     = pf0;
                *(bf16x8*)&xa[nb][prr][prs * 16 + 8] = pf1;
            }
            __syncthreads();   // single barrier: h[nxt] + wacc[par] (+ xa park) visible
            if (tid < 8) {     // tiny store, drains during next interval
                float v = 0.f;
                #pragma unroll
                for (int ww = 0; ww < 8; ++ww) v += wacc[par][ww][tid];
                partial[(size_t)dir * BL_ + (size_t)(b0 + tid) * L_ + l] = v;
            }
        }
    }
}

// ---------------- K5: out = sigmoid(pf + pb + bf)
__global__ __launch_bounds__(256) void k_final(
    const float* __restrict__ partial, const float* __restrict__ bfp,
    float* __restrict__ out) {
    const int i = blockIdx.x * 256 + threadIdx.x;
    if (i < BL_) out[i] = sigf(partial[i] + partial[BL_ + i] + bfp[0]);
}

extern "C" void kernel_launch(void* const* d_in, const int* in_sizes, int n_in,
                              void* d_out, int out_size, void* d_ws, size_t ws_size,
                              hipStream_t stream) {
    const float* rcv   = (const float*)d_in[0];
    const float* Wl    = (const float*)d_in[1];
    const float* bl    = (const float*)d_in[2];
    const float* Wih0f = (const float*)d_in[3];
    const float* Whh0f = (const float*)d_in[4];
    const float* bih0f = (const float*)d_in[5];
    const float* bhh0f = (const float*)d_in[6];
    const float* Wih0b = (const float*)d_in[7];
    const float* Whh0b = (const float*)d_in[8];
    const float* bih0b = (const float*)d_in[9];
    const float* bhh0b = (const float*)d_in[10];
    const float* Wih1f = (const float*)d_in[11];
    const float* Whh1f = (const float*)d_in[12];
    const float* bih1f = (const float*)d_in[13];
    const float* bhh1f = (const float*)d_in[14];
    const float* Wih1b = (const float*)d_in[15];
    const float* Whh1b = (const float*)d_in[16];
    const float* bih1b = (const float*)d_in[17];
    const float* bhh1b = (const float*)d_in[18];
    const float* Wfin  = (const float*)d_in[19];
    const float* bfin  = (const float*)d_in[20];

    const size_t OFF_CODE = 0;                     // 1,638,400 B
    const size_t OFF_PART = 1638400;               // 1,638,400 B
    const size_t OFF_H0   = 3276800;               // 104,857,600 B
    const size_t OFF_WBF  = 108134400;             //     393,216 B
    const size_t WS_NEEDED = 108527616;            // ~103.5 MB total

    if (ws_size < WS_NEEDED) {
        k_sentinel<<<(out_size + 255) / 256, 256, 0, stream>>>((float*)d_out, out_size);
        return;
    }

    char* ws = (char*)d_ws;
    float*  code    = (float*)(ws + OFF_CODE);
    float*  partial = (float*)(ws + OFF_PART);
    __bf16* h0      = (__bf16*)(ws + OFF_H0);
    __bf16* Wihbf   = (__bf16*)(ws + OFF_WBF);

    k_declin<<<256, 256, 0, stream>>>(rcv, Wl, bl, code);
    k_cvtW<<<192, 256, 0, stream>>>(Wih1f, Wih1b, Wihbf);
    k_gru0<<<dim3(128, 2), 512, 0, stream>>>(code, Wih0f, Whh0f, bih0f, bhh0f,
                                             Wih0b, Whh0b, bih0b, bhh0b, h0);
    k_gru1f<<<dim3(128, 2), 512, 0, stream>>>(h0, Wihbf,
                                              bih1f, bhh1f, bih1b, bhh1b,
                                              Whh1f, Whh1b, Wfin, partial);
    k_final<<<800, 256, 0, stream>>>(partial, bfin, (float*)d_out);
}

// Round 16
// 502.318 us; speedup vs baseline: 1.5269x; 1.2086x over previous
//
#include <hip/hip_runtime.h>
#include <hip/hip_bf16.h>

#define B_   1024
#define L_   200
#define H_   128
#define BL_  204800   // B_*L_
#define G3_  384

typedef __bf16 bf16x8 __attribute__((ext_vector_type(8)));
typedef __bf16 bf16x4 __attribute__((ext_vector_type(4)));
typedef float  f32x4  __attribute__((ext_vector_type(4)));

__device__ __forceinline__ float sigf(float x) {
    return __builtin_amdgcn_rcpf(1.f + __expf(-x));
}
__device__ __forceinline__ float tanh_fast(float x) {
    float e = __expf(-2.f * x);
    return (1.f - e) * __builtin_amdgcn_rcpf(1.f + e);
}
__device__ __forceinline__ bf16x8 cvt8(float4 a, float4 b) {
    bf16x8 v;
    v[0] = (__bf16)a.x; v[1] = (__bf16)a.y; v[2] = (__bf16)a.z; v[3] = (__bf16)a.w;
    v[4] = (__bf16)b.x; v[5] = (__bf16)b.y; v[6] = (__bf16)b.z; v[7] = (__bf16)b.w;
    return v;
}

// ---------------- K0: sentinel (workspace too small -> distinguishable absmax)
__global__ __launch_bounds__(256) void k_sentinel(float* __restrict__ out, int n) {
    const int i = blockIdx.x * 256 + threadIdx.x;
    if (i < n) out[i] = -5.0f;
}

// ---------------- K1: dec_linear
__global__ __launch_bounds__(256) void k_declin(
    const float* __restrict__ rcv, const float* __restrict__ Wl,
    const float* __restrict__ bl, float* __restrict__ code) {
    __shared__ float rs[4][400];
    const int tid = threadIdx.x;
    const int b0 = blockIdx.x * 4;
    for (int i = tid; i < 1600; i += 256) ((float*)rs)[i] = rcv[(size_t)b0 * 400 + i];
    __syncthreads();
    #pragma unroll
    for (int rep = 0; rep < 2; ++rep) {
        const int j = tid + rep * 256;
        if (j < 400) {
            float a0 = 0.f, a1 = 0.f, a2 = 0.f, a3 = 0.f;
            const float4* wp = (const float4*)(Wl + (size_t)j * 400);
            for (int k = 0; k < 100; ++k) {
                float4 w4 = wp[k];
                const int kk = k * 4;
                a0 += w4.x*rs[0][kk] + w4.y*rs[0][kk+1] + w4.z*rs[0][kk+2] + w4.w*rs[0][kk+3];
                a1 += w4.x*rs[1][kk] + w4.y*rs[1][kk+1] + w4.z*rs[1][kk+2] + w4.w*rs[1][kk+3];
                a2 += w4.x*rs[2][kk] + w4.y*rs[2][kk+1] + w4.z*rs[2][kk+2] + w4.w*rs[2][kk+3];
                a3 += w4.x*rs[3][kk] + w4.y*rs[3][kk+1] + w4.z*rs[3][kk+2] + w4.w*rs[3][kk+3];
            }
            const float bb = bl[j];
            code[(size_t)(b0+0)*400 + j] = a0 + bb;
            code[(size_t)(b0+1)*400 + j] = a1 + bb;
            code[(size_t)(b0+2)*400 + j] = a2 + bb;
            code[(size_t)(b0+3)*400 + j] = a3 + bb;
        }
    }
}

// ---------------- K2: layer0 GRU: tile=8, 8 symmetric waves, 256 blocks,
// one barrier/step, h double-buffered, h0 stores batched via LDS stage.
// Gate math spread across ALL 64 lanes (2 rows/lane via shfl_xor 32).
__global__ __launch_bounds__(512, 2) void k_gru0(
    const float* __restrict__ code,
    const float* __restrict__ Wih_f, const float* __restrict__ Whh_f,
    const float* __restrict__ bih_f, const float* __restrict__ bhh_f,
    const float* __restrict__ Wih_b, const float* __restrict__ Whh_b,
    const float* __restrict__ bih_b, const float* __restrict__ bhh_b,
    __bf16* __restrict__ h0) {
    const int dir = blockIdx.y;
    const int b0 = blockIdx.x * 8;
    const float* Wih = dir ? Wih_b : Wih_f;
    const float* Whh = dir ? Whh_b : Whh_f;
    const float* bih = dir ? bih_b : bih_f;
    const float* bhh = dir ? bhh_b : bhh_f;

    const int tid = threadIdx.x;
    const int w = tid >> 6, ln = tid & 63, q = ln >> 4, r16 = ln & 15;
    const int jj = w * 16 + r16;   // this wave's 16 output columns
    const bool low = (q < 2);
    const int mbase = (q & 1) * 4 + (q >> 1) * 2;   // this lane's 2 rows: mbase, mbase+1

    __shared__ __bf16 h_bf[2][16][136];      //  8,704 B (rows 8..15 zero pad)
    __shared__ float  code_s[8][400];        // 12,800 B
    __shared__ __bf16 h_st[2][8][8][128];    // 32,768 B stage [grp-par][s][row][col]

    for (int i = tid; i < 8 * 400; i += 512) ((float*)code_s)[i] = code[(size_t)b0 * 400 + i];
    for (int i = tid; i < 2 * 16 * 136; i += 512) ((__bf16*)h_bf)[i] = (__bf16)0.f;

    bf16x8 wfr[3][4];
    const float wr0 = Wih[jj * 2],         wr1 = Wih[jj * 2 + 1];
    const float wz0 = Wih[(jj + 128) * 2], wz1 = Wih[(jj + 128) * 2 + 1];
    const float wn0 = Wih[(jj + 256) * 2], wn1 = Wih[(jj + 256) * 2 + 1];
    const float xbr = bih[jj] + bhh[jj];
    const float xbz = bih[jj + 128] + bhh[jj + 128];
    const float xbn = bih[jj + 256];
    const float bnv = bhh[jj + 256];
    float hreg2[2] = {0.f, 0.f};
    #pragma unroll
    for (int g = 0; g < 3; ++g) {
        const int j = (w + g * 8) * 16 + r16;
        const float* p = Whh + (size_t)j * H_;
        #pragma unroll
        for (int kt = 0; kt < 4; ++kt) {
            float4 x0 = *(const float4*)(p + kt * 32 + q * 8);
            float4 x1 = *(const float4*)(p + kt * 32 + q * 8 + 4);
            wfr[g][kt] = cvt8(x0, x1);
        }
    }
    __syncthreads();

    for (int t = 0; t < L_; ++t) {
        const int cur = t & 1, nxt = cur ^ 1;
        // flush previous 8-step group (stores retire during this step's compute)
        if ((t & 7) == 0 && t > 0) {
            const int g8 = (t >> 3) - 1;
            const int buf = g8 & 1;
            const int p = tid >> 3, inner = tid & 7;     // 64 pairs x 8 threads
            const int s = p >> 3, row = p & 7;
            const int tb = g8 * 8 + s;
            const int l = dir ? (L_ - 1 - tb) : tb;
            const __bf16* src = &h_st[buf][s][row][inner * 16];
            __bf16* dst = &h0[((size_t)(b0 + row) * L_ + l) * 256 + dir * 128 + inner * 16];
            *(bf16x8*)(dst)     = *(const bf16x8*)(src);
            *(bf16x8*)(dst + 8) = *(const bf16x8*)(src + 8);
        }
        const int l = dir ? (L_ - 1 - t) : t;
        bf16x8 af[4];
        #pragma unroll
        for (int kt = 0; kt < 4; ++kt)
            af[kt] = *(const bf16x8*)&h_bf[cur][r16][kt * 32 + q * 8];

        f32x4 ar = {0.f,0.f,0.f,0.f}, az = {0.f,0.f,0.f,0.f}, an = {0.f,0.f,0.f,0.f};
        #pragma unroll
        for (int kt = 0; kt < 4; ++kt) {
            ar = __builtin_amdgcn_mfma_f32_16x16x32_bf16(af[kt], wfr[0][kt], ar, 0, 0, 0);
            az = __builtin_amdgcn_mfma_f32_16x16x32_bf16(af[kt], wfr[1][kt], az, 0, 0, 0);
            an = __builtin_amdgcn_mfma_f32_16x16x32_bf16(af[kt], wfr[2][kt], an, 0, 0, 0);
        }
        // spread: rows live in quadrants 0..1 (regs 0..3); lanes q>=2 take regs 2..3
        #pragma unroll
        for (int i = 0; i < 2; ++i) {
            const float tra = __shfl_xor(ar[i + 2], 32);
            const float tza = __shfl_xor(az[i + 2], 32);
            const float tna = __shfl_xor(an[i + 2], 32);
            const float arv = low ? ar[i] : tra;
            const float azv = low ? az[i] : tza;
            const float anv = low ? an[i] : tna;
            const int m = mbase + i;
            const float c0 = code_s[m][l * 2], c1 = code_s[m][l * 2 + 1];
            const float r = sigf(c0 * wr0 + c1 * wr1 + xbr + arv);
            const float z = sigf(c0 * wz0 + c1 * wz1 + xbz + azv);
            const float n = tanh_fast(c0 * wn0 + c1 * wn1 + xbn + r * (anv + bnv));
            const float hv = n + z * (hreg2[i] - n);
            hreg2[i] = hv;
            h_bf[nxt][m][jj] = (__bf16)hv;
            h_st[(t >> 3) & 1][t & 7][m][jj] = (__bf16)hv;
        }
        __syncthreads();   // single barrier: h[nxt] + stage visible
    }
    {   // final flush: group 24 (t=192..199), buf = 24&1 = 0
        const int p = tid >> 3, inner = tid & 7;
        const int s = p >> 3, row = p & 7;
        const int tb = 192 + s;
        const int l = dir ? (L_ - 1 - tb) : tb;
        const __bf16* src = &h_st[0][s][row][inner * 16];
        __bf16* dst = &h0[((size_t)(b0 + row) * L_ + l) * 256 + dir * 128 + inner * 16];
        *(bf16x8*)(dst)     = *(const bf16x8*)(src);
        *(bf16x8*)(dst + 8) = *(const bf16x8*)(src + 8);
    }
}

// ---------------- K3: convert Wih1 (both dirs) fp32 -> bf16  [2][384][256]
__global__ __launch_bounds__(256) void k_cvtW(
    const float* __restrict__ Wfp, const float* __restrict__ Wbp,
    __bf16* __restrict__ out) {
    const int j = blockIdx.x * 256 + threadIdx.x;
    const int base = j * 4;
    const int dir = base >= 98304;
    const int idx = dir ? base - 98304 : base;
    float4 v = *(const float4*)((dir ? Wbp : Wfp) + idx);
    bf16x4 o;
    o[0] = (__bf16)v.x; o[1] = (__bf16)v.y; o[2] = (__bf16)v.z; o[3] = (__bf16)v.w;
    *(bf16x4*)&out[base] = o;
}

// ---------------- K4: layer1 GRU — xg in registers (r15) + gate math spread
// across ALL 64 lanes (2 rows/lane). Wave w's GEMM n-tiles {w, w+8, w+16} =
// its own gate columns. A-chunk double-buffered with register prefetch.
__global__ __launch_bounds__(512, 2) void k_gru1f(
    const __bf16* __restrict__ h0,       // [B][L][256]
    const __bf16* __restrict__ Wihbf,    // [2][384][256] bf16
    const float* __restrict__ bih_f, const float* __restrict__ bhh_f,
    const float* __restrict__ bih_b, const float* __restrict__ bhh_b,
    const float* __restrict__ Whh_f, const float* __restrict__ Whh_b,
    const float* __restrict__ Wfin,
    float* __restrict__ partial) {
    const int dir = blockIdx.y;
    const int b0 = blockIdx.x * 8;
    const float* Whh = dir ? Whh_b : Whh_f;
    const float* bih = dir ? bih_b : bih_f;
    const float* bhh = dir ? bhh_b : bhh_f;
    const __bf16* Wb = Wihbf + (size_t)dir * 384 * 256;

    const int tid = threadIdx.x;
    const int w = tid >> 6, ln = tid & 63, q = ln >> 4, r16 = ln & 15;
    const int jj = w * 16 + r16;   // this wave's 16 recurrence columns
    const bool low = (q < 2);
    const int mbase = (q & 1) * 4 + (q >> 1) * 2;

    __shared__ __bf16 xa[2][32][264];    // 33,792 B  A-chunk dbuf (rows = s*8+bt)
    __shared__ __bf16 h_bf[2][16][136];  //  8,704 B  (rows 8..15 zero pad)
    __shared__ float  wacc[2][8][8];     //    512 B

    for (int i = tid; i < 2 * 16 * 136; i += 512) ((__bf16*)h_bf)[i] = (__bf16)0.f;

    bf16x8 wfr[3][4];
    bf16x8 wB[3][8];                      // register-resident Wih1 B-frags
    const float xbr = bih[jj] + bhh[jj];
    const float xbz = bih[jj + 128] + bhh[jj + 128];
    const float xbn = bih[jj + 256];
    const float bnv = bhh[jj + 256];
    const float wfv = Wfin[dir * 128 + jj];
    float hreg2[2] = {0.f, 0.f};
    #pragma unroll
    for (int g = 0; g < 3; ++g) {
        const int j = (w + g * 8) * 16 + r16;
        const float* p = Whh + (size_t)j * H_;
        #pragma unroll
        for (int kt = 0; kt < 4; ++kt) {
            float4 x0 = *(const float4*)(p + kt * 32 + q * 8);
            float4 x1 = *(const float4*)(p + kt * 32 + q * 8 + 4);
            wfr[g][kt] = cvt8(x0, x1);
        }
    }
    #pragma unroll
    for (int n = 0; n < 3; ++n) {
        const int ct = w + n * 8;        // tile ct -> cols jj + n*128
        const __bf16* wp = Wb + (size_t)(ct * 16 + r16) * 256 + q * 8;
        #pragma unroll
        for (int k8 = 0; k8 < 8; ++k8)
            wB[n][k8] = *(const bf16x8*)(wp + k8 * 32);
    }
    // prologue: stage chunk 0 into xa[0]
    {
        const int r = tid >> 4, seg = tid & 15;       // 32 rows x 16 threads
        const int s = r >> 3, bt = r & 7;
        const int l = dir ? (L_ - 1 - s) : s;         // t = s
        const __bf16* src = h0 + ((size_t)(b0 + bt) * L_ + l) * 256 + seg * 16;
        *(bf16x8*)&xa[0][r][seg * 16]     = *(const bf16x8*)(src);
        *(bf16x8*)&xa[0][r][seg * 16 + 8] = *(const bf16x8*)(src + 8);
    }
    __syncthreads();

    for (int c = 0; c < 50; ++c) {
        const int cb = c & 1, nb = cb ^ 1;
        // ---- issue prefetch loads for chunk c+1 (hidden under GEMM + 3 steps)
        bf16x8 pf0, pf1;
        const bool pv = (c + 1 < 50);
        const int prr = tid >> 4, prs = tid & 15;
        if (pv) {
            const int s = prr >> 3, bt = prr & 7;
            const int t = (c + 1) * 4 + s;
            const int l = dir ? (L_ - 1 - t) : t;
            const __bf16* src = h0 + ((size_t)(b0 + bt) * L_ + l) * 256 + prs * 16;
            pf0 = *(const bf16x8*)(src);
            pf1 = *(const bf16x8*)(src + 8);
        }

        // ---- chunk GEMM into persistent registers: accg[n][mt] holds
        // xg[row = mt*16 + tr][col = jj + n*128] in C-layout
        f32x4 accg[3][2];
        #pragma unroll
        for (int n = 0; n < 3; ++n)
            #pragma unroll
            for (int mt = 0; mt < 2; ++mt) {
                accg[n][mt][0]=0.f; accg[n][mt][1]=0.f;
                accg[n][mt][2]=0.f; accg[n][mt][3]=0.f;
            }
        #pragma unroll
        for (int k8 = 0; k8 < 8; ++k8) {
            const bf16x8 a0 = *(const bf16x8*)&xa[cb][r16][k8 * 32 + q * 8];
            const bf16x8 a1 = *(const bf16x8*)&xa[cb][16 + r16][k8 * 32 + q * 8];
            #pragma unroll
            for (int n = 0; n < 3; ++n) {
                accg[n][0] = __builtin_amdgcn_mfma_f32_16x16x32_bf16(a0, wB[n][k8], accg[n][0], 0, 0, 0);
                accg[n][1] = __builtin_amdgcn_mfma_f32_16x16x32_bf16(a1, wB[n][k8], accg[n][1], 0, 0, 0);
            }
        }

        // ---- 4 recurrent steps, one barrier each
        #pragma unroll
        for (int s = 0; s < 4; ++s) {
            const int cur = s & 1, nxt = cur ^ 1;   // gstep = 4c+s, 4c even
            const int par = s & 1;
            const int t = c * 4 + s;
            const int l = dir ? (L_ - 1 - t) : t;
            const int mt = s >> 1;

            bf16x8 af[4];
            #pragma unroll
            for (int kt = 0; kt < 4; ++kt)
                af[kt] = *(const bf16x8*)&h_bf[cur][r16][kt * 32 + q * 8];

            f32x4 ar = {0.f,0.f,0.f,0.f}, az = {0.f,0.f,0.f,0.f}, an = {0.f,0.f,0.f,0.f};
            #pragma unroll
            for (int kt = 0; kt < 4; ++kt) {
                ar = __builtin_amdgcn_mfma_f32_16x16x32_bf16(af[kt], wfr[0][kt], ar, 0, 0, 0);
                az = __builtin_amdgcn_mfma_f32_16x16x32_bf16(af[kt], wfr[1][kt], az, 0, 0, 0);
                an = __builtin_amdgcn_mfma_f32_16x16x32_bf16(af[kt], wfr[2][kt], an, 0, 0, 0);
            }

            float hv2[2];
            #pragma unroll
            for (int i = 0; i < 2; ++i) {
                // xg for row mbase+i at tile-row (s&1)*8 + m:
                // even s: quadrants 0..1 hold rows (lanes q>=2 fetch regs 2..3);
                // odd s: quadrants 2..3 hold rows (lanes q<2 fetch regs 0..1).
                float xrv, xzv, xnv;
                if ((s & 1) == 0) {
                    const float t0 = __shfl_xor(accg[0][mt][i + 2], 32);
                    const float t1 = __shfl_xor(accg[1][mt][i + 2], 32);
                    const float t2 = __shfl_xor(accg[2][mt][i + 2], 32);
                    xrv = low ? accg[0][mt][i] : t0;
                    xzv = low ? accg[1][mt][i] : t1;
                    xnv = low ? accg[2][mt][i] : t2;
                } else {
                    const float t0 = __shfl_xor(accg[0][mt][i], 32);
                    const float t1 = __shfl_xor(accg[1][mt][i], 32);
                    const float t2 = __shfl_xor(accg[2][mt][i], 32);
                    xrv = low ? t0 : accg[0][mt][i + 2];
                    xzv = low ? t1 : accg[1][mt][i + 2];
                    xnv = low ? t2 : accg[2][mt][i + 2];
                }
                const float tra = __shfl_xor(ar[i + 2], 32);
                const float tza = __shfl_xor(az[i + 2], 32);
                const float tna = __shfl_xor(an[i + 2], 32);
                const float arv = low ? ar[i] : tra;
                const float azv = low ? az[i] : tza;
                const float anv = low ? an[i] : tna;
                const int m = mbase + i;
                const float r = sigf(xrv + xbr + arv);
                const float z = sigf(xzv + xbz + azv);
                const float n = tanh_fast(xnv + xbn + r * (anv + bnv));
                const float hv = n + z * (hreg2[i] - n);
                hreg2[i] = hv;
                hv2[i] = hv;
                h_bf[nxt][m][jj] = (__bf16)hv;
            }
            // fused final-linear partial dot: reduce over r16 within quadrant
            #pragma unroll
            for (int i = 0; i < 2; ++i) {
                float v = hv2[i] * wfv;
                v += __shfl_xor(v, 1); v += __shfl_xor(v, 2);
                v += __shfl_xor(v, 4); v += __shfl_xor(v, 8);
                if (r16 == 0) wacc[par][w][mbase + i] = v;
            }
            // park prefetched chunk c+1 into xa[nb]; published by this barrier
            if (pv && s == 2) {
                *(bf16x8*)&xa[nb][prr][prs * 16]     = pf0;
                *(bf16x8*)&xa[nb][prr][prs * 16 + 8] = pf1;
            }
            __syncthreads();   // single barrier: h[nxt] + wacc[par] (+ xa park) visible
            if (tid < 8) {     // tiny store, drains during next interval
                float v = 0.f;
                #pragma unroll
                for (int ww = 0; ww < 8; ++ww) v += wacc[par][ww][tid];
                partial[(size_t)dir * BL_ + (size_t)(b0 + tid) * L_ + l] = v;
            }
        }
    }
}

// ---------------- K5: out = sigmoid(pf + pb + bf)
__global__ __launch_bounds__(256) void k_final(
    const float* __restrict__ partial, const float* __restrict__ bfp,
    float* __restrict__ out) {
    const int i = blockIdx.x * 256 + threadIdx.x;
    if (i < BL_) out[i] = sigf(partial[i] + partial[BL_ + i] + bfp[0]);
}

extern "C" void kernel_launch(void* const* d_in, const int* in_sizes, int n_in,
                              void* d_out, int out_size, void* d_ws, size_t ws_size,
                              hipStream_t stream) {
    const float* rcv   = (const float*)d_in[0];
    const float* Wl    = (const float*)d_in[1];
    const float* bl    = (const float*)d_in[2];
    const float* Wih0f = (const float*)d_in[3];
    const float* Whh0f = (const float*)d_in[4];
    const float* bih0f = (const float*)d_in[5];
    const float* bhh0f = (const float*)d_in[6];
    const float* Wih0b = (const float*)d_in[7];
    const float* Whh0b = (const float*)d_in[8];
    const float* bih0b = (const float*)d_in[9];
    const float* bhh0b = (const float*)d_in[10];
    const float* Wih1f = (const float*)d_in[11];
    const float* Whh1f = (const float*)d_in[12];
    const float* bih1f = (const float*)d_in[13];
    const float* bhh1f = (const float*)d_in[14];
    const float* Wih1b = (const float*)d_in[15];
    const float* Whh1b = (const float*)d_in[16];
    const float* bih1b = (const float*)d_in[17];
    const float* bhh1b = (const float*)d_in[18];
    const float* Wfin  = (const float*)d_in[19];
    const float* bfin  = (const float*)d_in[20];

    const size_t OFF_CODE = 0;                     // 1,638,400 B
    const size_t OFF_PART = 1638400;               // 1,638,400 B
    const size_t OFF_H0   = 3276800;               // 104,857,600 B
    const size_t OFF_WBF  = 108134400;             //     393,216 B
    const size_t WS_NEEDED = 108527616;            // ~103.5 MB total

    if (ws_size < WS_NEEDED) {
        k_sentinel<<<(out_size + 255) / 256, 256, 0, stream>>>((float*)d_out, out_size);
        return;
    }

    char* ws = (char*)d_ws;
    float*  code    = (float*)(ws + OFF_CODE);
    float*  partial = (float*)(ws + OFF_PART);
    __bf16* h0      = (__bf16*)(ws + OFF_H0);
    __bf16* Wihbf   = (__bf16*)(ws + OFF_WBF);

    k_declin<<<256, 256, 0, stream>>>(rcv, Wl, bl, code);
    k_cvtW<<<192, 256, 0, stream>>>(Wih1f, Wih1b, Wihbf);
    k_gru0<<<dim3(128, 2), 512, 0, stream>>>(code, Wih0f, Whh0f, bih0f, bhh0f,
                                             Wih0b, Whh0b, bih0b, bhh0b, h0);
    k_gru1f<<<dim3(128, 2), 512, 0, stream>>>(h0, Wihbf,
                                              bih1f, bhh1f, bih1b, bhh1b,
                                              Whh1f, Whh1b, Wfin, partial);
    k_final<<<800, 256, 0, stream>>>(partial, bfin, (float*)d_out);
}